// Round 1
// baseline (654.942 us; speedup 1.0000x reference)
//
#include <hip/hip_runtime.h>
#include <cstdint>
#include <cstddef>

static constexpr int NN = 100000;
static constexpr int NE = 1600000;
static constexpr float NEG = 0.2f;

// ---------------------------------------------------------------------------
// Projection: src_fc = feat @ Wsrc^T ; out = feat @ Wdst^T + b_dst
// Each thread owns one weight row (128 f32, register-resident).
// feat row address is wave-uniform -> scalar loads, no LDS, no barriers.
// ---------------------------------------------------------------------------
__global__ __launch_bounds__(256) void proj_kernel(
    const float* __restrict__ feat, const float* __restrict__ Wsrc,
    const float* __restrict__ Wdst, const float* __restrict__ bdst,
    float* __restrict__ src_fc, float* __restrict__ out)
{
  const int t = threadIdx.x;
  const float* wrow = (t < 128) ? (Wsrc + t * 128) : (Wdst + (t - 128) * 128);
  float w[128];
#pragma unroll
  for (int k = 0; k < 128; k += 4) {
    float4 v = *(const float4*)(wrow + k);
    w[k] = v.x; w[k + 1] = v.y; w[k + 2] = v.z; w[k + 3] = v.w;
  }
  const float bias = (t >= 128) ? bdst[t - 128] : 0.0f;
  const int n0 = blockIdx.x * 32;
  const int n1 = min(n0 + 32, NN);
  for (int n = n0; n < n1; ++n) {
    const float* frow = feat + (size_t)n * 128;
    float acc = 0.0f;
#pragma unroll
    for (int k = 0; k < 128; ++k) acc = fmaf(frow[k], w[k], acc);
    if (t < 128) src_fc[(size_t)n * 128 + t] = acc;
    else         out[(size_t)n * 128 + (t - 128)] = acc + bias;
  }
}

// ---------------------------------------------------------------------------
// Attention projections: attn[n*4 + {0,1,2,3}] = {as0, as1, ad0, ad1}
// 4 threads per node, each one dot product of length 128.
// ---------------------------------------------------------------------------
__global__ __launch_bounds__(256) void attn_kernel(
    const float* __restrict__ feat, const float* __restrict__ asrc,
    const float* __restrict__ adst, float* __restrict__ attn)
{
  const int idx = blockIdx.x * blockDim.x + threadIdx.x;
  const int n = idx >> 2;
  const int r = idx & 3;
  if (n >= NN) return;
  const float* arow = (r < 2) ? (asrc + r * 128) : (adst + (r - 2) * 128);
  const float* frow = feat + (size_t)n * 128;
  float acc = 0.0f;
#pragma unroll
  for (int k = 0; k < 128; k += 4) {
    float4 f = *(const float4*)(frow + k);
    float4 a = *(const float4*)(arow + k);
    acc += f.x * a.x + f.y * a.y + f.z * a.z + f.w * a.w;
  }
  attn[idx] = acc;
}

// ---------------------------------------------------------------------------
// Histogram of destination nodes.
// ---------------------------------------------------------------------------
__global__ void hist_kernel(const int* __restrict__ dst, int* __restrict__ cnt)
{
  const int e = blockIdx.x * blockDim.x + threadIdx.x;
  if (e < NE) atomicAdd(&cnt[dst[e]], 1);
}

// ---------------------------------------------------------------------------
// 3-kernel exclusive scan over cnt[0..NN) -> rs[0..NN], and next = rs copy.
// ---------------------------------------------------------------------------
__global__ __launch_bounds__(1024) void scan_block_sums(
    const int* __restrict__ cnt, int* __restrict__ bsum)
{
  __shared__ int lds[1024];
  const int i = blockIdx.x * 1024 + threadIdx.x;
  lds[threadIdx.x] = (i < NN) ? cnt[i] : 0;
  __syncthreads();
  for (int o = 512; o > 0; o >>= 1) {
    if (threadIdx.x < o) lds[threadIdx.x] += lds[threadIdx.x + o];
    __syncthreads();
  }
  if (threadIdx.x == 0) bsum[blockIdx.x] = lds[0];
}

__global__ void scan_partials(int* __restrict__ bsum, int nb)
{
  __shared__ int lds[128];
  const int t = threadIdx.x;
  const int v = (t < nb) ? bsum[t] : 0;
  lds[t] = v;
  __syncthreads();
  int x = v;
  for (int o = 1; o < 128; o <<= 1) {
    const int y = (t >= o) ? lds[t - o] : 0;
    __syncthreads();
    x += y;
    lds[t] = x;
    __syncthreads();
  }
  if (t < nb) bsum[t] = x - v;  // exclusive
}

__global__ __launch_bounds__(1024) void scan_final(
    const int* __restrict__ cnt, const int* __restrict__ bsum,
    int* __restrict__ rs, int* __restrict__ next)
{
  __shared__ int lds[1024];
  const int t = threadIdx.x;
  const int i = blockIdx.x * 1024 + t;
  const int v = (i < NN) ? cnt[i] : 0;
  lds[t] = v;
  __syncthreads();
  int x = v;
  for (int o = 1; o < 1024; o <<= 1) {
    const int y = (t >= o) ? lds[t - o] : 0;
    __syncthreads();
    x += y;
    lds[t] = x;
    __syncthreads();
  }
  const int excl = x - v + bsum[blockIdx.x];
  if (i < NN) { rs[i] = excl; next[i] = excl; }
  if (i == NN - 1) rs[NN] = excl + v;
}

// ---------------------------------------------------------------------------
// Scatter edges into CSR buckets (order within bucket nondeterministic; only
// perturbs f32 summation order, well inside tolerance).
// ---------------------------------------------------------------------------
__global__ void scatter_kernel(const int* __restrict__ src, const int* __restrict__ dst,
                               int* __restrict__ next, int* __restrict__ csr_src)
{
  const int e = blockIdx.x * blockDim.x + threadIdx.x;
  if (e >= NE) return;
  const int d = dst[e];
  const int pos = atomicAdd(&next[d], 1);
  csr_src[pos] = src[e];
}

// ---------------------------------------------------------------------------
// Aggregation: one wave (64 lanes) per destination node. Lane l owns output
// features {2l, 2l+1}; lanes 0..31 are head 0, lanes 32..63 head 1.
// Softmax denominators computed in-wave (no segment-max needed: logits are
// O(10), exp is exact-safe in f32, normalization is scale-invariant).
// ---------------------------------------------------------------------------
__global__ __launch_bounds__(256) void aggregate_kernel(
    const int* __restrict__ rs, const int* __restrict__ csr_src,
    const float* __restrict__ attn, const float* __restrict__ src_fc,
    float* __restrict__ out)
{
  const int wid = (int)((blockIdx.x * (size_t)blockDim.x + threadIdx.x) >> 6);
  if (wid >= NN) return;
  const int lane = threadIdx.x & 63;
  const int start = rs[wid];
  const int end = rs[wid + 1];
  if (end == start) return;  // isolated node: out already holds feat_dst_fc

  const float ad0 = attn[4 * wid + 2];
  const float ad1 = attn[4 * wid + 3];

  // denominator pass
  float d0 = 0.0f, d1 = 0.0f;
  for (int i = start + lane; i < end; i += 64) {
    const int s = csr_src[i];
    float e0 = attn[4 * s + 0] + ad0;
    float e1 = attn[4 * s + 1] + ad1;
    e0 = (e0 > 0.0f) ? e0 : NEG * e0;
    e1 = (e1 > 0.0f) ? e1 : NEG * e1;
    d0 += __expf(e0);
    d1 += __expf(e1);
  }
#pragma unroll
  for (int o = 32; o > 0; o >>= 1) {
    d0 += __shfl_xor(d0, o, 64);
    d1 += __shfl_xor(d1, o, 64);
  }
  const float inv = (lane < 32) ? (1.0f / d0) : (1.0f / d1);

  // weighted accumulation
  const int f = lane * 2;
  float acc0 = 0.0f, acc1 = 0.0f;
  for (int i = start; i < end; ++i) {
    const int s = csr_src[i];  // uniform -> scalar load
    float e0 = attn[4 * s + 0] + ad0;
    float e1 = attn[4 * s + 1] + ad1;
    e0 = (e0 > 0.0f) ? e0 : NEG * e0;
    e1 = (e1 > 0.0f) ? e1 : NEG * e1;
    const float eh = (lane < 32) ? e0 : e1;
    const float wgt = __expf(eh);
    const float2 v = *(const float2*)(src_fc + (size_t)s * 128 + f);
    acc0 = fmaf(v.x, wgt, acc0);
    acc1 = fmaf(v.y, wgt, acc1);
  }
  float2* po = (float2*)(out + (size_t)wid * 128 + f);
  float2 cur = *po;
  cur.x = fmaf(acc0, inv, cur.x);
  cur.y = fmaf(acc1, inv, cur.y);
  *po = cur;
}

// ---------------------------------------------------------------------------
extern "C" void kernel_launch(void* const* d_in, const int* in_sizes, int n_in,
                              void* d_out, int out_size, void* d_ws, size_t ws_size,
                              hipStream_t stream)
{
  const float* feat   = (const float*)d_in[0];
  const int*   src_idx = (const int*)d_in[1];
  const int*   dst_idx = (const int*)d_in[2];
  const float* Wsrc   = (const float*)d_in[3];
  const float* Wdst   = (const float*)d_in[4];
  const float* bdst   = (const float*)d_in[5];
  const float* asrc   = (const float*)d_in[6];
  const float* adst   = (const float*)d_in[7];
  float* out = (float*)d_out;

  char* ws = (char*)d_ws;
  size_t off = 0;
  auto alloc = [&](size_t bytes) -> void* {
    void* p = ws + off;
    off = (off + bytes + 255) & ~(size_t)255;
    return p;
  };
  float* src_fc  = (float*)alloc((size_t)NN * 128 * sizeof(float)); // 51.2 MB
  float* attn    = (float*)alloc((size_t)NN * 4 * sizeof(float));   // 1.6 MB
  int*   cnt     = (int*)alloc((size_t)NN * sizeof(int));
  int*   rs      = (int*)alloc((size_t)(NN + 1) * sizeof(int));
  int*   next    = (int*)alloc((size_t)NN * sizeof(int));
  int*   csr_src = (int*)alloc((size_t)NE * sizeof(int));           // 6.4 MB
  int*   bsum    = (int*)alloc(128 * sizeof(int));

  hipMemsetAsync(cnt, 0, (size_t)NN * sizeof(int), stream);

  proj_kernel<<<(NN + 31) / 32, 256, 0, stream>>>(feat, Wsrc, Wdst, bdst, src_fc, out);
  attn_kernel<<<(NN * 4 + 255) / 256, 256, 0, stream>>>(feat, asrc, adst, attn);
  hist_kernel<<<(NE + 255) / 256, 256, 0, stream>>>(dst_idx, cnt);

  constexpr int NB = (NN + 1023) / 1024;  // 98
  scan_block_sums<<<NB, 1024, 0, stream>>>(cnt, bsum);
  scan_partials<<<1, 128, 0, stream>>>(bsum, NB);
  scan_final<<<NB, 1024, 0, stream>>>(cnt, bsum, rs, next);

  scatter_kernel<<<(NE + 255) / 256, 256, 0, stream>>>(src_idx, dst_idx, next, csr_src);
  aggregate_kernel<<<(NN * 64) / 256, 256, 0, stream>>>(rs, csr_src, attn, src_fc, out);
}

// Round 2
// 479.587 us; speedup vs baseline: 1.3656x; 1.3656x over previous
//
#include <hip/hip_runtime.h>
#include <cstdint>
#include <cstddef>

static constexpr int NN = 100000;
static constexpr int NE = 1600000;
static constexpr float NEG = 0.2f;

typedef __attribute__((ext_vector_type(8))) short short8v;   // 8 bf16 (4 VGPRs)
typedef __attribute__((ext_vector_type(4))) float floatx4;   // 4 f32 acc

// ---------------------------------------------------------------------------
// f32 -> bf16 (RNE) of 8 consecutive values held in two float4s.
// ---------------------------------------------------------------------------
__device__ inline short8v cvt8(const float4 a, const float4 b)
{
  const float v[8] = {a.x, a.y, a.z, a.w, b.x, b.y, b.z, b.w};
  uint32_t q[8];
#pragma unroll
  for (int j = 0; j < 8; ++j) {
    uint32_t u = __float_as_uint(v[j]);
    u += 0x7fff + ((u >> 16) & 1);   // round-to-nearest-even
    q[j] = u >> 16;
  }
  union { uint32_t u[4]; short8v s; } r;
  r.u[0] = q[0] | (q[1] << 16);
  r.u[1] = q[2] | (q[3] << 16);
  r.u[2] = q[4] | (q[5] << 16);
  r.u[3] = q[6] | (q[7] << 16);
  return r.s;
}

// ---------------------------------------------------------------------------
// Convert Wsrc (128x128) and Wdst (128x128) f32 -> one bf16 matrix wb[256][128]
// (rows 0-127 = Wsrc, rows 128-255 = Wdst), row-major in K.
// ---------------------------------------------------------------------------
__global__ __launch_bounds__(256) void cvt_w_kernel(
    const float* __restrict__ Wsrc, const float* __restrict__ Wdst,
    ushort* __restrict__ wb)
{
  const int i = (blockIdx.x * 256 + threadIdx.x) * 8;
  if (i >= 32768) return;
  const float* src = (i < 16384) ? (Wsrc + i) : (Wdst + (i - 16384));
  float4 a = *(const float4*)(src);
  float4 b = *(const float4*)(src + 4);
  short8v s = cvt8(a, b);
  *(short8v*)(wb + i) = s;
}

// ---------------------------------------------------------------------------
// MFMA projection GEMM: [100000,128] x [128,256] -> src_fc (cols 0-127),
// out = . + b_dst (cols 128-255).  A = feat (f32, converted to bf16 in-flight),
// B = wb bf16, register-resident per wave (each wave owns 64 columns).
// Grid-strided over 6250 M-tiles of 16 rows.
// ---------------------------------------------------------------------------
__global__ __launch_bounds__(256) void gemm_kernel(
    const float* __restrict__ feat, const ushort* __restrict__ wb,
    const float* __restrict__ bdst,
    float* __restrict__ src_fc, float* __restrict__ out)
{
  const int lane = threadIdx.x & 63;
  const int w    = threadIdx.x >> 6;       // wave 0..3
  const int c0   = w * 64;                 // column base of this wave
  const int colq = lane & 15;              // N / M row index within tile
  const int kgrp = lane >> 4;              // 0..3, k-group of 8

  // B fragments: 16 x short8v = 64 VGPRs, loaded once (L2-resident weights).
  short8v bf[4][4];
#pragma unroll
  for (int nt = 0; nt < 4; ++nt)
#pragma unroll
    for (int kt = 0; kt < 4; ++kt)
      bf[nt][kt] = *(const short8v*)(wb + (size_t)(c0 + nt * 16 + colq) * 128
                                        + kt * 32 + kgrp * 8);

  float bias[4];
#pragma unroll
  for (int nt = 0; nt < 4; ++nt) {
    const int col = c0 + nt * 16 + colq;
    bias[nt] = (col >= 128) ? bdst[col - 128] : 0.0f;
  }
  const bool is_dst = (c0 >= 128);         // wave-uniform

  for (int mt = blockIdx.x; mt < NN / 16; mt += gridDim.x) {
    const int row0 = mt * 16;
    // A fragments: row = row0 + colq, k = kt*32 + kgrp*8 + j  (f32 -> bf16)
    short8v af[4];
#pragma unroll
    for (int kt = 0; kt < 4; ++kt) {
      const float* ap = feat + (size_t)(row0 + colq) * 128 + kt * 32 + kgrp * 8;
      float4 a = *(const float4*)ap;
      float4 b = *(const float4*)(ap + 4);
      af[kt] = cvt8(a, b);
    }
    floatx4 acc[4] = {{0,0,0,0},{0,0,0,0},{0,0,0,0},{0,0,0,0}};
#pragma unroll
    for (int kt = 0; kt < 4; ++kt)
#pragma unroll
      for (int nt = 0; nt < 4; ++nt)
        acc[nt] = __builtin_amdgcn_mfma_f32_16x16x32_bf16(af[kt], bf[nt][kt],
                                                          acc[nt], 0, 0, 0);
    // C/D: col = lane&15, row = (lane>>4)*4 + reg   [verified mapping]
#pragma unroll
    for (int nt = 0; nt < 4; ++nt) {
      const int col = c0 + nt * 16 + colq;
#pragma unroll
      for (int j = 0; j < 4; ++j) {
        const int rr = row0 + kgrp * 4 + j;
        if (!is_dst) src_fc[(size_t)rr * 128 + col] = acc[nt][j];
        else         out[(size_t)rr * 128 + (col - 128)] = acc[nt][j] + bias[nt];
      }
    }
  }
}

// ---------------------------------------------------------------------------
// Attention projections: attn[n*4 + {0,1,2,3}] = {as0, as1, ad0, ad1}
// ---------------------------------------------------------------------------
__global__ __launch_bounds__(256) void attn_kernel(
    const float* __restrict__ feat, const float* __restrict__ asrc,
    const float* __restrict__ adst, float* __restrict__ attn)
{
  const int idx = blockIdx.x * blockDim.x + threadIdx.x;
  const int n = idx >> 2;
  const int r = idx & 3;
  if (n >= NN) return;
  const float* arow = (r < 2) ? (asrc + r * 128) : (adst + (r - 2) * 128);
  const float* frow = feat + (size_t)n * 128;
  float acc = 0.0f;
#pragma unroll
  for (int k = 0; k < 128; k += 4) {
    float4 f = *(const float4*)(frow + k);
    float4 a = *(const float4*)(arow + k);
    acc += f.x * a.x + f.y * a.y + f.z * a.z + f.w * a.w;
  }
  attn[idx] = acc;
}

// ---------------------------------------------------------------------------
__global__ void hist_kernel(const int* __restrict__ dst, int* __restrict__ cnt)
{
  const int e = blockIdx.x * blockDim.x + threadIdx.x;
  if (e < NE) atomicAdd(&cnt[dst[e]], 1);
}

__global__ __launch_bounds__(1024) void scan_block_sums(
    const int* __restrict__ cnt, int* __restrict__ bsum)
{
  __shared__ int lds[1024];
  const int i = blockIdx.x * 1024 + threadIdx.x;
  lds[threadIdx.x] = (i < NN) ? cnt[i] : 0;
  __syncthreads();
  for (int o = 512; o > 0; o >>= 1) {
    if (threadIdx.x < o) lds[threadIdx.x] += lds[threadIdx.x + o];
    __syncthreads();
  }
  if (threadIdx.x == 0) bsum[blockIdx.x] = lds[0];
}

__global__ void scan_partials(int* __restrict__ bsum, int nb)
{
  __shared__ int lds[128];
  const int t = threadIdx.x;
  const int v = (t < nb) ? bsum[t] : 0;
  lds[t] = v;
  __syncthreads();
  int x = v;
  for (int o = 1; o < 128; o <<= 1) {
    const int y = (t >= o) ? lds[t - o] : 0;
    __syncthreads();
    x += y;
    lds[t] = x;
    __syncthreads();
  }
  if (t < nb) bsum[t] = x - v;  // exclusive
}

__global__ __launch_bounds__(1024) void scan_final(
    const int* __restrict__ cnt, const int* __restrict__ bsum,
    int* __restrict__ rs, int* __restrict__ next)
{
  __shared__ int lds[1024];
  const int t = threadIdx.x;
  const int i = blockIdx.x * 1024 + t;
  const int v = (i < NN) ? cnt[i] : 0;
  lds[t] = v;
  __syncthreads();
  int x = v;
  for (int o = 1; o < 1024; o <<= 1) {
    const int y = (t >= o) ? lds[t - o] : 0;
    __syncthreads();
    x += y;
    lds[t] = x;
    __syncthreads();
  }
  const int excl = x - v + bsum[blockIdx.x];
  if (i < NN) { rs[i] = excl; next[i] = excl; }
  if (i == NN - 1) rs[NN] = excl + v;
}

__global__ void scatter_kernel(const int* __restrict__ src, const int* __restrict__ dst,
                               int* __restrict__ next, int* __restrict__ csr_src)
{
  const int e = blockIdx.x * blockDim.x + threadIdx.x;
  if (e >= NE) return;
  const int d = dst[e];
  const int pos = atomicAdd(&next[d], 1);
  csr_src[pos] = src[e];
}

// ---------------------------------------------------------------------------
// Aggregation: one wave per destination node (unchanged from R0).
// ---------------------------------------------------------------------------
__global__ __launch_bounds__(256) void aggregate_kernel(
    const int* __restrict__ rs, const int* __restrict__ csr_src,
    const float* __restrict__ attn, const float* __restrict__ src_fc,
    float* __restrict__ out)
{
  const int wid = (int)((blockIdx.x * (size_t)blockDim.x + threadIdx.x) >> 6);
  if (wid >= NN) return;
  const int lane = threadIdx.x & 63;
  const int start = rs[wid];
  const int end = rs[wid + 1];
  if (end == start) return;

  const float ad0 = attn[4 * wid + 2];
  const float ad1 = attn[4 * wid + 3];

  float d0 = 0.0f, d1 = 0.0f;
  for (int i = start + lane; i < end; i += 64) {
    const int s = csr_src[i];
    float e0 = attn[4 * s + 0] + ad0;
    float e1 = attn[4 * s + 1] + ad1;
    e0 = (e0 > 0.0f) ? e0 : NEG * e0;
    e1 = (e1 > 0.0f) ? e1 : NEG * e1;
    d0 += __expf(e0);
    d1 += __expf(e1);
  }
#pragma unroll
  for (int o = 32; o > 0; o >>= 1) {
    d0 += __shfl_xor(d0, o, 64);
    d1 += __shfl_xor(d1, o, 64);
  }
  const float inv = (lane < 32) ? (1.0f / d0) : (1.0f / d1);

  const int f = lane * 2;
  float acc0 = 0.0f, acc1 = 0.0f;
  for (int i = start; i < end; ++i) {
    const int s = csr_src[i];
    float e0 = attn[4 * s + 0] + ad0;
    float e1 = attn[4 * s + 1] + ad1;
    e0 = (e0 > 0.0f) ? e0 : NEG * e0;
    e1 = (e1 > 0.0f) ? e1 : NEG * e1;
    const float eh = (lane < 32) ? e0 : e1;
    const float wgt = __expf(eh);
    const float2 v = *(const float2*)(src_fc + (size_t)s * 128 + f);
    acc0 = fmaf(v.x, wgt, acc0);
    acc1 = fmaf(v.y, wgt, acc1);
  }
  float2* po = (float2*)(out + (size_t)wid * 128 + f);
  float2 cur = *po;
  cur.x = fmaf(acc0, inv, cur.x);
  cur.y = fmaf(acc1, inv, cur.y);
  *po = cur;
}

// ---------------------------------------------------------------------------
extern "C" void kernel_launch(void* const* d_in, const int* in_sizes, int n_in,
                              void* d_out, int out_size, void* d_ws, size_t ws_size,
                              hipStream_t stream)
{
  const float* feat    = (const float*)d_in[0];
  const int*   src_idx = (const int*)d_in[1];
  const int*   dst_idx = (const int*)d_in[2];
  const float* Wsrc    = (const float*)d_in[3];
  const float* Wdst    = (const float*)d_in[4];
  const float* bdst    = (const float*)d_in[5];
  const float* asrc    = (const float*)d_in[6];
  const float* adst    = (const float*)d_in[7];
  float* out = (float*)d_out;

  char* ws = (char*)d_ws;
  size_t off = 0;
  auto alloc = [&](size_t bytes) -> void* {
    void* p = ws + off;
    off = (off + bytes + 255) & ~(size_t)255;
    return p;
  };
  float*  src_fc  = (float*)alloc((size_t)NN * 128 * sizeof(float)); // 51.2 MB
  float*  attn    = (float*)alloc((size_t)NN * 4 * sizeof(float));   // 1.6 MB
  int*    cnt     = (int*)alloc((size_t)NN * sizeof(int));
  int*    rs      = (int*)alloc((size_t)(NN + 1) * sizeof(int));
  int*    next    = (int*)alloc((size_t)NN * sizeof(int));
  int*    csr_src = (int*)alloc((size_t)NE * sizeof(int));           // 6.4 MB
  int*    bsum    = (int*)alloc(128 * sizeof(int));
  ushort* wb      = (ushort*)alloc((size_t)256 * 128 * sizeof(ushort)); // 64 KB

  hipMemsetAsync(cnt, 0, (size_t)NN * sizeof(int), stream);

  cvt_w_kernel<<<16, 256, 0, stream>>>(Wsrc, Wdst, wb);
  gemm_kernel<<<2048, 256, 0, stream>>>(feat, wb, bdst, src_fc, out);
  attn_kernel<<<(NN * 4 + 255) / 256, 256, 0, stream>>>(feat, asrc, adst, attn);
  hist_kernel<<<(NE + 255) / 256, 256, 0, stream>>>(dst_idx, cnt);

  constexpr int NB = (NN + 1023) / 1024;  // 98
  scan_block_sums<<<NB, 1024, 0, stream>>>(cnt, bsum);
  scan_partials<<<1, 128, 0, stream>>>(bsum, NB);
  scan_final<<<NB, 1024, 0, stream>>>(cnt, bsum, rs, next);

  scatter_kernel<<<(NE + 255) / 256, 256, 0, stream>>>(src_idx, dst_idx, next, csr_src);
  aggregate_kernel<<<(NN * 64) / 256, 256, 0, stream>>>(rs, csr_src, attn, src_fc, out);
}

// Round 3
// 403.678 us; speedup vs baseline: 1.6224x; 1.1880x over previous
//
#include <hip/hip_runtime.h>
#include <cstdint>
#include <cstddef>

static constexpr int NN = 100000;
static constexpr int NE = 1600000;
static constexpr float NEG = 0.2f;

typedef __attribute__((ext_vector_type(8))) short short8v;   // 8 bf16 (4 VGPRs)
typedef __attribute__((ext_vector_type(4))) float floatx4;   // 4 f32 acc

// ---------------------------------------------------------------------------
__device__ inline short8v cvt8(const float4 a, const float4 b)
{
  const float v[8] = {a.x, a.y, a.z, a.w, b.x, b.y, b.z, b.w};
  uint32_t q[8];
#pragma unroll
  for (int j = 0; j < 8; ++j) {
    uint32_t u = __float_as_uint(v[j]);
    u += 0x7fff + ((u >> 16) & 1);   // round-to-nearest-even
    q[j] = u >> 16;
  }
  union { uint32_t u[4]; short8v s; } r;
  r.u[0] = q[0] | (q[1] << 16);
  r.u[1] = q[2] | (q[3] << 16);
  r.u[2] = q[4] | (q[5] << 16);
  r.u[3] = q[6] | (q[7] << 16);
  return r.s;
}

__device__ inline ushort cvt1(float x)
{
  uint32_t u = __float_as_uint(x);
  u += 0x7fff + ((u >> 16) & 1);
  return (ushort)(u >> 16);
}

// ---------------------------------------------------------------------------
// Convert Wsrc/Wdst (each 128x128 f32) -> wb[256][128] bf16.
// ---------------------------------------------------------------------------
__global__ __launch_bounds__(256) void cvt_w_kernel(
    const float* __restrict__ Wsrc, const float* __restrict__ Wdst,
    ushort* __restrict__ wb)
{
  const int i = (blockIdx.x * 256 + threadIdx.x) * 8;
  if (i >= 32768) return;
  const float* src = (i < 16384) ? (Wsrc + i) : (Wdst + (i - 16384));
  float4 a = *(const float4*)(src);
  float4 b = *(const float4*)(src + 4);
  short8v s = cvt8(a, b);
  *(short8v*)(wb + i) = s;
}

// ---------------------------------------------------------------------------
// MFMA projection GEMM: A = feat (f32 -> bf16 in-flight), B = wb register-
// resident. Cols 0-127 -> src_fc (bf16), cols 128-255 -> out (f32, + bias).
// ---------------------------------------------------------------------------
__global__ __launch_bounds__(256) void gemm_kernel(
    const float* __restrict__ feat, const ushort* __restrict__ wb,
    const float* __restrict__ bdst,
    ushort* __restrict__ src_fc, float* __restrict__ out)
{
  const int lane = threadIdx.x & 63;
  const int w    = threadIdx.x >> 6;       // wave 0..3
  const int c0   = w * 64;
  const int colq = lane & 15;
  const int kgrp = lane >> 4;

  short8v bf[4][4];
#pragma unroll
  for (int nt = 0; nt < 4; ++nt)
#pragma unroll
    for (int kt = 0; kt < 4; ++kt)
      bf[nt][kt] = *(const short8v*)(wb + (size_t)(c0 + nt * 16 + colq) * 128
                                        + kt * 32 + kgrp * 8);

  float bias[4];
#pragma unroll
  for (int nt = 0; nt < 4; ++nt) {
    const int col = c0 + nt * 16 + colq;
    bias[nt] = (col >= 128) ? bdst[col - 128] : 0.0f;
  }
  const bool is_dst = (c0 >= 128);

  for (int mt = blockIdx.x; mt < NN / 16; mt += gridDim.x) {
    const int row0 = mt * 16;
    short8v af[4];
#pragma unroll
    for (int kt = 0; kt < 4; ++kt) {
      const float* ap = feat + (size_t)(row0 + colq) * 128 + kt * 32 + kgrp * 8;
      float4 a = *(const float4*)ap;
      float4 b = *(const float4*)(ap + 4);
      af[kt] = cvt8(a, b);
    }
    floatx4 acc[4] = {{0,0,0,0},{0,0,0,0},{0,0,0,0},{0,0,0,0}};
#pragma unroll
    for (int kt = 0; kt < 4; ++kt)
#pragma unroll
      for (int nt = 0; nt < 4; ++nt)
        acc[nt] = __builtin_amdgcn_mfma_f32_16x16x32_bf16(af[kt], bf[nt][kt],
                                                          acc[nt], 0, 0, 0);
    // C/D: col = lane&15, row = (lane>>4)*4 + reg
#pragma unroll
    for (int nt = 0; nt < 4; ++nt) {
      const int col = c0 + nt * 16 + colq;
#pragma unroll
      for (int j = 0; j < 4; ++j) {
        const int rr = row0 + kgrp * 4 + j;
        if (!is_dst) src_fc[(size_t)rr * 128 + col] = cvt1(acc[nt][j]);
        else         out[(size_t)rr * 128 + (col - 128)] = acc[nt][j] + bias[nt];
      }
    }
  }
}

// ---------------------------------------------------------------------------
// Attention projections -> attn_s[n] = (as0, as1), attn_d[n] = (ad0, ad1).
// ---------------------------------------------------------------------------
__global__ __launch_bounds__(256) void attn_kernel(
    const float* __restrict__ feat, const float* __restrict__ asrc,
    const float* __restrict__ adst, float* __restrict__ attn_s,
    float* __restrict__ attn_d)
{
  const int idx = blockIdx.x * blockDim.x + threadIdx.x;
  const int n = idx >> 2;
  const int r = idx & 3;
  if (n >= NN) return;
  const float* arow = (r < 2) ? (asrc + r * 128) : (adst + (r - 2) * 128);
  const float* frow = feat + (size_t)n * 128;
  float acc = 0.0f;
#pragma unroll
  for (int k = 0; k < 128; k += 4) {
    float4 f = *(const float4*)(frow + k);
    float4 a = *(const float4*)(arow + k);
    acc += f.x * a.x + f.y * a.y + f.z * a.z + f.w * a.w;
  }
  if (r < 2) attn_s[2 * n + r] = acc;
  else       attn_d[2 * n + (r - 2)] = acc;
}

// ---------------------------------------------------------------------------
__global__ void hist_kernel(const int* __restrict__ dst, int* __restrict__ cnt)
{
  const int e = blockIdx.x * blockDim.x + threadIdx.x;
  if (e < NE) atomicAdd(&cnt[dst[e]], 1);
}

__global__ __launch_bounds__(1024) void scan_block_sums(
    const int* __restrict__ cnt, int* __restrict__ bsum)
{
  __shared__ int lds[1024];
  const int i = blockIdx.x * 1024 + threadIdx.x;
  lds[threadIdx.x] = (i < NN) ? cnt[i] : 0;
  __syncthreads();
  for (int o = 512; o > 0; o >>= 1) {
    if (threadIdx.x < o) lds[threadIdx.x] += lds[threadIdx.x + o];
    __syncthreads();
  }
  if (threadIdx.x == 0) bsum[blockIdx.x] = lds[0];
}

__global__ void scan_partials(int* __restrict__ bsum, int nb)
{
  __shared__ int lds[128];
  const int t = threadIdx.x;
  const int v = (t < nb) ? bsum[t] : 0;
  lds[t] = v;
  __syncthreads();
  int x = v;
  for (int o = 1; o < 128; o <<= 1) {
    const int y = (t >= o) ? lds[t - o] : 0;
    __syncthreads();
    x += y;
    lds[t] = x;
    __syncthreads();
  }
  if (t < nb) bsum[t] = x - v;  // exclusive
}

__global__ __launch_bounds__(1024) void scan_final(
    const int* __restrict__ cnt, const int* __restrict__ bsum,
    int* __restrict__ rs, int* __restrict__ next)
{
  __shared__ int lds[1024];
  const int t = threadIdx.x;
  const int i = blockIdx.x * 1024 + t;
  const int v = (i < NN) ? cnt[i] : 0;
  lds[t] = v;
  __syncthreads();
  int x = v;
  for (int o = 1; o < 1024; o <<= 1) {
    const int y = (t >= o) ? lds[t - o] : 0;
    __syncthreads();
    x += y;
    lds[t] = x;
    __syncthreads();
  }
  const int excl = x - v + bsum[blockIdx.x];
  if (i < NN) { rs[i] = excl; next[i] = excl; }
  if (i == NN - 1) rs[NN] = excl + v;
}

__global__ void scatter_kernel(const int* __restrict__ src, const int* __restrict__ dst,
                               int* __restrict__ next, int* __restrict__ csr_src)
{
  const int e = blockIdx.x * blockDim.x + threadIdx.x;
  if (e >= NE) return;
  const int d = dst[e];
  const int pos = atomicAdd(&next[d], 1);
  csr_src[pos] = src[e];
}

// ---------------------------------------------------------------------------
// Aggregation: one wave per destination node, SINGLE fused pass.
// Lane l owns bf16 features {2l, 2l+1}; lanes 0-31 head 0, 32-63 head 1.
// Every lane redundantly computes each edge's weight (broadcast loads) and
// accumulates the softmax denominator alongside the weighted feature sum.
// 2-deep software pipeline hides gather latency.
// ---------------------------------------------------------------------------
__global__ __launch_bounds__(256) void aggregate_kernel(
    const int* __restrict__ rs, const int* __restrict__ csr_src,
    const float2* __restrict__ attn_s, const float2* __restrict__ attn_d,
    const ushort* __restrict__ src_fc, float* __restrict__ out)
{
  int wid = (int)((blockIdx.x * (size_t)blockDim.x + threadIdx.x) >> 6);
  if (wid >= NN) return;
  wid = __builtin_amdgcn_readfirstlane(wid);
  const int lane = threadIdx.x & 63;
  const int start = rs[wid];
  const int end = rs[wid + 1];
  if (end == start) return;   // isolated node: out already = feat_dst_fc

  const float2 ad = attn_d[wid];
  const bool h0 = (lane < 32);
  const float adh = h0 ? ad.x : ad.y;

  // prologue of the 2-deep pipeline
  int s = csr_src[start];
  float2 as = attn_s[s];
  uint32_t rowbits = *(const uint32_t*)(src_fc + (size_t)s * 128 + 2 * lane);

  float acc0 = 0.0f, acc1 = 0.0f, denom = 0.0f;
  for (int i = start; i < end; ++i) {
    const float2  as_c = as;
    const uint32_t rb_c = rowbits;
    if (i + 1 < end) {
      const int s2 = csr_src[i + 1];
      as = attn_s[s2];
      rowbits = *(const uint32_t*)(src_fc + (size_t)s2 * 128 + 2 * lane);
    }
    float e = (h0 ? as_c.x : as_c.y) + adh;
    e = (e > 0.0f) ? e : NEG * e;
    const float wgt = __expf(e);
    denom += wgt;
    const float v0 = __uint_as_float(rb_c << 16);          // feature 2*lane
    const float v1 = __uint_as_float(rb_c & 0xffff0000u);  // feature 2*lane+1
    acc0 = fmaf(v0, wgt, acc0);
    acc1 = fmaf(v1, wgt, acc1);
  }
  const float inv = 1.0f / denom;
  float2* po = (float2*)(out + (size_t)wid * 128 + 2 * lane);
  float2 cur = *po;
  cur.x = fmaf(acc0, inv, cur.x);
  cur.y = fmaf(acc1, inv, cur.y);
  *po = cur;
}

// ---------------------------------------------------------------------------
extern "C" void kernel_launch(void* const* d_in, const int* in_sizes, int n_in,
                              void* d_out, int out_size, void* d_ws, size_t ws_size,
                              hipStream_t stream)
{
  const float* feat    = (const float*)d_in[0];
  const int*   src_idx = (const int*)d_in[1];
  const int*   dst_idx = (const int*)d_in[2];
  const float* Wsrc    = (const float*)d_in[3];
  const float* Wdst    = (const float*)d_in[4];
  const float* bdst    = (const float*)d_in[5];
  const float* asrc    = (const float*)d_in[6];
  const float* adst    = (const float*)d_in[7];
  float* out = (float*)d_out;

  char* ws = (char*)d_ws;
  size_t off = 0;
  auto alloc = [&](size_t bytes) -> void* {
    void* p = ws + off;
    off = (off + bytes + 255) & ~(size_t)255;
    return p;
  };
  ushort* src_fc  = (ushort*)alloc((size_t)NN * 128 * sizeof(ushort)); // 25.6 MB
  float*  attn_s  = (float*)alloc((size_t)NN * 2 * sizeof(float));
  float*  attn_d  = (float*)alloc((size_t)NN * 2 * sizeof(float));
  int*    cnt     = (int*)alloc((size_t)NN * sizeof(int));
  int*    rs      = (int*)alloc((size_t)(NN + 1) * sizeof(int));
  int*    next    = (int*)alloc((size_t)NN * sizeof(int));
  int*    csr_src = (int*)alloc((size_t)NE * sizeof(int));             // 6.4 MB
  int*    bsum    = (int*)alloc(128 * sizeof(int));
  ushort* wb      = (ushort*)alloc((size_t)256 * 128 * sizeof(ushort));

  hipMemsetAsync(cnt, 0, (size_t)NN * sizeof(int), stream);

  cvt_w_kernel<<<16, 256, 0, stream>>>(Wsrc, Wdst, wb);
  gemm_kernel<<<2048, 256, 0, stream>>>(feat, wb, bdst, src_fc, out);
  attn_kernel<<<(NN * 4 + 255) / 256, 256, 0, stream>>>(feat, asrc, adst, attn_s, attn_d);
  hist_kernel<<<(NE + 255) / 256, 256, 0, stream>>>(dst_idx, cnt);

  constexpr int NB = (NN + 1023) / 1024;  // 98
  scan_block_sums<<<NB, 1024, 0, stream>>>(cnt, bsum);
  scan_partials<<<1, 128, 0, stream>>>(bsum, NB);
  scan_final<<<NB, 1024, 0, stream>>>(cnt, bsum, rs, next);

  scatter_kernel<<<(NE + 255) / 256, 256, 0, stream>>>(src_idx, dst_idx, next, csr_src);
  aggregate_kernel<<<(NN * 64) / 256, 256, 0, stream>>>(
      rs, csr_src, (const float2*)attn_s, (const float2*)attn_d, src_fc, out);
}

// Round 4
// 350.798 us; speedup vs baseline: 1.8670x; 1.1507x over previous
//
#include <hip/hip_runtime.h>
#include <cstdint>
#include <cstddef>

static constexpr int NN = 100000;
static constexpr int NE = 1600000;
static constexpr float NEG = 0.2f;
static constexpr int NPART = 8;                 // == #XCDs
static constexpr int PART_SZ = NN / NPART;      // 12500
static constexpr int BLK_PER_PART = 256;
static constexpr int CHUNK = NE / BLK_PER_PART; // 6250

typedef __attribute__((ext_vector_type(8))) short short8v;   // 8 bf16 (4 VGPRs)
typedef __attribute__((ext_vector_type(4))) float floatx4;   // 4 f32 acc

// ---------------------------------------------------------------------------
__device__ inline short8v cvt8(const float4 a, const float4 b)
{
  const float v[8] = {a.x, a.y, a.z, a.w, b.x, b.y, b.z, b.w};
  uint32_t q[8];
#pragma unroll
  for (int j = 0; j < 8; ++j) {
    uint32_t u = __float_as_uint(v[j]);
    u += 0x7fff + ((u >> 16) & 1);   // round-to-nearest-even
    q[j] = u >> 16;
  }
  union { uint32_t u[4]; short8v s; } r;
  r.u[0] = q[0] | (q[1] << 16);
  r.u[1] = q[2] | (q[3] << 16);
  r.u[2] = q[4] | (q[5] << 16);
  r.u[3] = q[6] | (q[7] << 16);
  return r.s;
}

__device__ inline ushort cvt1(float x)
{
  uint32_t u = __float_as_uint(x);
  u += 0x7fff + ((u >> 16) & 1);
  return (ushort)(u >> 16);
}

// ---------------------------------------------------------------------------
__global__ __launch_bounds__(256) void cvt_w_kernel(
    const float* __restrict__ Wsrc, const float* __restrict__ Wdst,
    ushort* __restrict__ wb)
{
  const int i = (blockIdx.x * 256 + threadIdx.x) * 8;
  if (i >= 32768) return;
  const float* src = (i < 16384) ? (Wsrc + i) : (Wdst + (i - 16384));
  float4 a = *(const float4*)(src);
  float4 b = *(const float4*)(src + 4);
  short8v s = cvt8(a, b);
  *(short8v*)(wb + i) = s;
}

// ---------------------------------------------------------------------------
// MFMA projection GEMM: A = feat (f32 -> bf16 in-flight), B = wb register-
// resident. Cols 0-127 -> src_fc (bf16), cols 128-255 -> out (f32, + bias).
// ---------------------------------------------------------------------------
__global__ __launch_bounds__(256) void gemm_kernel(
    const float* __restrict__ feat, const ushort* __restrict__ wb,
    const float* __restrict__ bdst,
    ushort* __restrict__ src_fc, float* __restrict__ out)
{
  const int lane = threadIdx.x & 63;
  const int w    = threadIdx.x >> 6;       // wave 0..3
  const int c0   = w * 64;
  const int colq = lane & 15;
  const int kgrp = lane >> 4;

  short8v bf[4][4];
#pragma unroll
  for (int nt = 0; nt < 4; ++nt)
#pragma unroll
    for (int kt = 0; kt < 4; ++kt)
      bf[nt][kt] = *(const short8v*)(wb + (size_t)(c0 + nt * 16 + colq) * 128
                                        + kt * 32 + kgrp * 8);

  float bias[4];
#pragma unroll
  for (int nt = 0; nt < 4; ++nt) {
    const int col = c0 + nt * 16 + colq;
    bias[nt] = (col >= 128) ? bdst[col - 128] : 0.0f;
  }
  const bool is_dst = (c0 >= 128);

  for (int mt = blockIdx.x; mt < NN / 16; mt += gridDim.x) {
    const int row0 = mt * 16;
    short8v af[4];
#pragma unroll
    for (int kt = 0; kt < 4; ++kt) {
      const float* ap = feat + (size_t)(row0 + colq) * 128 + kt * 32 + kgrp * 8;
      float4 a = *(const float4*)ap;
      float4 b = *(const float4*)(ap + 4);
      af[kt] = cvt8(a, b);
    }
    floatx4 acc[4] = {{0,0,0,0},{0,0,0,0},{0,0,0,0},{0,0,0,0}};
#pragma unroll
    for (int kt = 0; kt < 4; ++kt)
#pragma unroll
      for (int nt = 0; nt < 4; ++nt)
        acc[nt] = __builtin_amdgcn_mfma_f32_16x16x32_bf16(af[kt], bf[nt][kt],
                                                          acc[nt], 0, 0, 0);
    // C/D: col = lane&15, row = (lane>>4)*4 + reg
#pragma unroll
    for (int nt = 0; nt < 4; ++nt) {
      const int col = c0 + nt * 16 + colq;
#pragma unroll
      for (int j = 0; j < 4; ++j) {
        const int rr = row0 + kgrp * 4 + j;
        if (!is_dst) src_fc[(size_t)rr * 128 + col] = cvt1(acc[nt][j]);
        else         out[(size_t)rr * 128 + (col - 128)] = acc[nt][j] + bias[nt];
      }
    }
  }
}

// ---------------------------------------------------------------------------
// Attention projections -> attn_s[n] = (as0, as1), attn_d[n] = (ad0, ad1).
// ---------------------------------------------------------------------------
__global__ __launch_bounds__(256) void attn_kernel(
    const float* __restrict__ feat, const float* __restrict__ asrc,
    const float* __restrict__ adst, float* __restrict__ attn_s,
    float* __restrict__ attn_d)
{
  const int idx = blockIdx.x * blockDim.x + threadIdx.x;
  const int n = idx >> 2;
  const int r = idx & 3;
  if (n >= NN) return;
  const float* arow = (r < 2) ? (asrc + r * 128) : (adst + (r - 2) * 128);
  const float* frow = feat + (size_t)n * 128;
  float acc = 0.0f;
#pragma unroll
  for (int k = 0; k < 128; k += 4) {
    float4 f = *(const float4*)(frow + k);
    float4 a = *(const float4*)(arow + k);
    acc += f.x * a.x + f.y * a.y + f.z * a.z + f.w * a.w;
  }
  if (r < 2) attn_s[2 * n + r] = acc;
  else       attn_d[2 * n + (r - 2)] = acc;
}

// ---------------------------------------------------------------------------
// XCD-partitioned histogram: block b only counts dst in partition (b&7).
// Under round-robin dispatch each cnt line is touched by one XCD only.
// ---------------------------------------------------------------------------
__global__ __launch_bounds__(256) void hist_kernel(
    const int* __restrict__ dst, int* __restrict__ cnt)
{
  const int part = blockIdx.x & (NPART - 1);
  const int blk  = blockIdx.x >> 3;
  const unsigned lo = part * PART_SZ;
  const int e0 = blk * CHUNK;
  const int e1 = min(e0 + CHUNK, NE);
  for (int e = e0 + threadIdx.x; e < e1; e += 256) {
    const int d = dst[e];
    if ((unsigned)(d - lo) < (unsigned)PART_SZ) atomicAdd(&cnt[d], 1);
  }
}

__global__ __launch_bounds__(1024) void scan_block_sums(
    const int* __restrict__ cnt, int* __restrict__ bsum)
{
  __shared__ int lds[1024];
  const int i = blockIdx.x * 1024 + threadIdx.x;
  lds[threadIdx.x] = (i < NN) ? cnt[i] : 0;
  __syncthreads();
  for (int o = 512; o > 0; o >>= 1) {
    if (threadIdx.x < o) lds[threadIdx.x] += lds[threadIdx.x + o];
    __syncthreads();
  }
  if (threadIdx.x == 0) bsum[blockIdx.x] = lds[0];
}

__global__ void scan_partials(int* __restrict__ bsum, int nb)
{
  __shared__ int lds[128];
  const int t = threadIdx.x;
  const int v = (t < nb) ? bsum[t] : 0;
  lds[t] = v;
  __syncthreads();
  int x = v;
  for (int o = 1; o < 128; o <<= 1) {
    const int y = (t >= o) ? lds[t - o] : 0;
    __syncthreads();
    x += y;
    lds[t] = x;
    __syncthreads();
  }
  if (t < nb) bsum[t] = x - v;  // exclusive
}

__global__ __launch_bounds__(1024) void scan_final(
    const int* __restrict__ cnt, const int* __restrict__ bsum,
    int* __restrict__ rs, int* __restrict__ next)
{
  __shared__ int lds[1024];
  const int t = threadIdx.x;
  const int i = blockIdx.x * 1024 + t;
  const int v = (i < NN) ? cnt[i] : 0;
  lds[t] = v;
  __syncthreads();
  int x = v;
  for (int o = 1; o < 1024; o <<= 1) {
    const int y = (t >= o) ? lds[t - o] : 0;
    __syncthreads();
    x += y;
    lds[t] = x;
    __syncthreads();
  }
  const int excl = x - v + bsum[blockIdx.x];
  if (i < NN) { rs[i] = excl; next[i] = excl; }
  if (i == NN - 1) rs[NN] = excl + v;
}

// ---------------------------------------------------------------------------
// XCD-partitioned scatter: block b only handles dst in partition (b&7), so a
// given node's csr bucket line is written by a single XCD and its 16 entries
// merge in that XCD's L2 (one flush instead of ~16 cross-XCD line bounces).
// ---------------------------------------------------------------------------
__global__ __launch_bounds__(256) void scatter_kernel(
    const int* __restrict__ src, const int* __restrict__ dst,
    int* __restrict__ next, int* __restrict__ csr_src)
{
  const int part = blockIdx.x & (NPART - 1);
  const int blk  = blockIdx.x >> 3;
  const unsigned lo = part * PART_SZ;
  const int e0 = blk * CHUNK;
  const int e1 = min(e0 + CHUNK, NE);
  for (int e = e0 + threadIdx.x; e < e1; e += 256) {
    const int d = dst[e];
    if ((unsigned)(d - lo) < (unsigned)PART_SZ) {
      const int pos = atomicAdd(&next[d], 1);
      csr_src[pos] = src[e];
    }
  }
}

// ---------------------------------------------------------------------------
// Aggregation: one wave per destination node, single fused pass (unchanged).
// ---------------------------------------------------------------------------
__global__ __launch_bounds__(256) void aggregate_kernel(
    const int* __restrict__ rs, const int* __restrict__ csr_src,
    const float2* __restrict__ attn_s, const float2* __restrict__ attn_d,
    const ushort* __restrict__ src_fc, float* __restrict__ out)
{
  int wid = (int)((blockIdx.x * (size_t)blockDim.x + threadIdx.x) >> 6);
  if (wid >= NN) return;
  wid = __builtin_amdgcn_readfirstlane(wid);
  const int lane = threadIdx.x & 63;
  const int start = rs[wid];
  const int end = rs[wid + 1];
  if (end == start) return;   // isolated node: out already = feat_dst_fc

  const float2 ad = attn_d[wid];
  const bool h0 = (lane < 32);
  const float adh = h0 ? ad.x : ad.y;

  int s = csr_src[start];
  float2 as = attn_s[s];
  uint32_t rowbits = *(const uint32_t*)(src_fc + (size_t)s * 128 + 2 * lane);

  float acc0 = 0.0f, acc1 = 0.0f, denom = 0.0f;
  for (int i = start; i < end; ++i) {
    const float2  as_c = as;
    const uint32_t rb_c = rowbits;
    if (i + 1 < end) {
      const int s2 = csr_src[i + 1];
      as = attn_s[s2];
      rowbits = *(const uint32_t*)(src_fc + (size_t)s2 * 128 + 2 * lane);
    }
    float e = (h0 ? as_c.x : as_c.y) + adh;
    e = (e > 0.0f) ? e : NEG * e;
    const float wgt = __expf(e);
    denom += wgt;
    const float v0 = __uint_as_float(rb_c << 16);          // feature 2*lane
    const float v1 = __uint_as_float(rb_c & 0xffff0000u);  // feature 2*lane+1
    acc0 = fmaf(v0, wgt, acc0);
    acc1 = fmaf(v1, wgt, acc1);
  }
  const float inv = 1.0f / denom;
  float2* po = (float2*)(out + (size_t)wid * 128 + 2 * lane);
  float2 cur = *po;
  cur.x = fmaf(acc0, inv, cur.x);
  cur.y = fmaf(acc1, inv, cur.y);
  *po = cur;
}

// ---------------------------------------------------------------------------
extern "C" void kernel_launch(void* const* d_in, const int* in_sizes, int n_in,
                              void* d_out, int out_size, void* d_ws, size_t ws_size,
                              hipStream_t stream)
{
  const float* feat    = (const float*)d_in[0];
  const int*   src_idx = (const int*)d_in[1];
  const int*   dst_idx = (const int*)d_in[2];
  const float* Wsrc    = (const float*)d_in[3];
  const float* Wdst    = (const float*)d_in[4];
  const float* bdst    = (const float*)d_in[5];
  const float* asrc    = (const float*)d_in[6];
  const float* adst    = (const float*)d_in[7];
  float* out = (float*)d_out;

  char* ws = (char*)d_ws;
  size_t off = 0;
  auto alloc = [&](size_t bytes) -> void* {
    void* p = ws + off;
    off = (off + bytes + 255) & ~(size_t)255;
    return p;
  };
  ushort* src_fc  = (ushort*)alloc((size_t)NN * 128 * sizeof(ushort)); // 25.6 MB
  float*  attn_s  = (float*)alloc((size_t)NN * 2 * sizeof(float));
  float*  attn_d  = (float*)alloc((size_t)NN * 2 * sizeof(float));
  int*    cnt     = (int*)alloc((size_t)NN * sizeof(int));
  int*    rs      = (int*)alloc((size_t)(NN + 1) * sizeof(int));
  int*    next    = (int*)alloc((size_t)NN * sizeof(int));
  int*    csr_src = (int*)alloc((size_t)NE * sizeof(int));             // 6.4 MB
  int*    bsum    = (int*)alloc(128 * sizeof(int));
  ushort* wb      = (ushort*)alloc((size_t)256 * 128 * sizeof(ushort));

  hipMemsetAsync(cnt, 0, (size_t)NN * sizeof(int), stream);

  cvt_w_kernel<<<16, 256, 0, stream>>>(Wsrc, Wdst, wb);
  gemm_kernel<<<2048, 256, 0, stream>>>(feat, wb, bdst, src_fc, out);
  attn_kernel<<<(NN * 4 + 255) / 256, 256, 0, stream>>>(feat, asrc, adst, attn_s, attn_d);
  hist_kernel<<<BLK_PER_PART * NPART, 256, 0, stream>>>(dst_idx, cnt);

  constexpr int NB = (NN + 1023) / 1024;  // 98
  scan_block_sums<<<NB, 1024, 0, stream>>>(cnt, bsum);
  scan_partials<<<1, 128, 0, stream>>>(bsum, NB);
  scan_final<<<NB, 1024, 0, stream>>>(cnt, bsum, rs, next);

  scatter_kernel<<<BLK_PER_PART * NPART, 256, 0, stream>>>(src_idx, dst_idx, next, csr_src);
  aggregate_kernel<<<(NN * 64) / 256, 256, 0, stream>>>(
      rs, csr_src, (const float2*)attn_s, (const float2*)attn_d, src_fc, out);
}

// Round 5
// 320.683 us; speedup vs baseline: 2.0423x; 1.0939x over previous
//
#include <hip/hip_runtime.h>
#include <cstdint>
#include <cstddef>

static constexpr int NN = 100000;
static constexpr int NE = 1600000;
static constexpr float NEG = 0.2f;
static constexpr int NPART = 8;                 // == #XCDs
static constexpr int PART_SZ = NN / NPART;      // 12500
static constexpr int BLK_PER_PART = 256;
static constexpr int CHUNK = NE / BLK_PER_PART; // 6250

typedef __attribute__((ext_vector_type(8))) short short8v;   // 8 bf16 (4 VGPRs)
typedef __attribute__((ext_vector_type(4))) float floatx4;   // 4 f32 acc

// ---------------------------------------------------------------------------
__device__ inline short8v cvt8(const float4 a, const float4 b)
{
  const float v[8] = {a.x, a.y, a.z, a.w, b.x, b.y, b.z, b.w};
  uint32_t q[8];
#pragma unroll
  for (int j = 0; j < 8; ++j) {
    uint32_t u = __float_as_uint(v[j]);
    u += 0x7fff + ((u >> 16) & 1);   // round-to-nearest-even
    q[j] = u >> 16;
  }
  union { uint32_t u[4]; short8v s; } r;
  r.u[0] = q[0] | (q[1] << 16);
  r.u[1] = q[2] | (q[3] << 16);
  r.u[2] = q[4] | (q[5] << 16);
  r.u[3] = q[6] | (q[7] << 16);
  return r.s;
}

__device__ inline ushort cvt1(float x)
{
  uint32_t u = __float_as_uint(x);
  u += 0x7fff + ((u >> 16) & 1);
  return (ushort)(u >> 16);
}

// ---------------------------------------------------------------------------
__global__ __launch_bounds__(256) void cvt_w_kernel(
    const float* __restrict__ Wsrc, const float* __restrict__ Wdst,
    ushort* __restrict__ wb)
{
  const int i = (blockIdx.x * 256 + threadIdx.x) * 8;
  if (i >= 32768) return;
  const float* src = (i < 16384) ? (Wsrc + i) : (Wdst + (i - 16384));
  float4 a = *(const float4*)(src);
  float4 b = *(const float4*)(src + 4);
  short8v s = cvt8(a, b);
  *(short8v*)(wb + i) = s;
}

// ---------------------------------------------------------------------------
// MFMA projection GEMM: A = feat (f32 -> bf16 in-flight), B = wb register-
// resident. Cols 0-127 -> src_fc (bf16), cols 128-255 -> out (f32, + bias).
// ---------------------------------------------------------------------------
__global__ __launch_bounds__(256) void gemm_kernel(
    const float* __restrict__ feat, const ushort* __restrict__ wb,
    const float* __restrict__ bdst,
    ushort* __restrict__ src_fc, float* __restrict__ out)
{
  const int lane = threadIdx.x & 63;
  const int w    = threadIdx.x >> 6;       // wave 0..3
  const int c0   = w * 64;
  const int colq = lane & 15;
  const int kgrp = lane >> 4;

  short8v bf[4][4];
#pragma unroll
  for (int nt = 0; nt < 4; ++nt)
#pragma unroll
    for (int kt = 0; kt < 4; ++kt)
      bf[nt][kt] = *(const short8v*)(wb + (size_t)(c0 + nt * 16 + colq) * 128
                                        + kt * 32 + kgrp * 8);

  float bias[4];
#pragma unroll
  for (int nt = 0; nt < 4; ++nt) {
    const int col = c0 + nt * 16 + colq;
    bias[nt] = (col >= 128) ? bdst[col - 128] : 0.0f;
  }
  const bool is_dst = (c0 >= 128);

  for (int mt = blockIdx.x; mt < NN / 16; mt += gridDim.x) {
    const int row0 = mt * 16;
    short8v af[4];
#pragma unroll
    for (int kt = 0; kt < 4; ++kt) {
      const float* ap = feat + (size_t)(row0 + colq) * 128 + kt * 32 + kgrp * 8;
      float4 a = *(const float4*)ap;
      float4 b = *(const float4*)(ap + 4);
      af[kt] = cvt8(a, b);
    }
    floatx4 acc[4] = {{0,0,0,0},{0,0,0,0},{0,0,0,0},{0,0,0,0}};
#pragma unroll
    for (int kt = 0; kt < 4; ++kt)
#pragma unroll
      for (int nt = 0; nt < 4; ++nt)
        acc[nt] = __builtin_amdgcn_mfma_f32_16x16x32_bf16(af[kt], bf[nt][kt],
                                                          acc[nt], 0, 0, 0);
    // C/D: col = lane&15, row = (lane>>4)*4 + reg
#pragma unroll
    for (int nt = 0; nt < 4; ++nt) {
      const int col = c0 + nt * 16 + colq;
#pragma unroll
      for (int j = 0; j < 4; ++j) {
        const int rr = row0 + kgrp * 4 + j;
        if (!is_dst) src_fc[(size_t)rr * 128 + col] = cvt1(acc[nt][j]);
        else         out[(size_t)rr * 128 + (col - 128)] = acc[nt][j] + bias[nt];
      }
    }
  }
}

// ---------------------------------------------------------------------------
// Attention projections -> attn_s[n] = (as0, as1), attn_d[n] = (ad0, ad1).
// ---------------------------------------------------------------------------
__global__ __launch_bounds__(256) void attn_kernel(
    const float* __restrict__ feat, const float* __restrict__ asrc,
    const float* __restrict__ adst, float* __restrict__ attn_s,
    float* __restrict__ attn_d)
{
  const int idx = blockIdx.x * blockDim.x + threadIdx.x;
  const int n = idx >> 2;
  const int r = idx & 3;
  if (n >= NN) return;
  const float* arow = (r < 2) ? (asrc + r * 128) : (adst + (r - 2) * 128);
  const float* frow = feat + (size_t)n * 128;
  float acc = 0.0f;
#pragma unroll
  for (int k = 0; k < 128; k += 4) {
    float4 f = *(const float4*)(frow + k);
    float4 a = *(const float4*)(arow + k);
    acc += f.x * a.x + f.y * a.y + f.z * a.z + f.w * a.w;
  }
  if (r < 2) attn_s[2 * n + r] = acc;
  else       attn_d[2 * n + (r - 2)] = acc;
}

// ---------------------------------------------------------------------------
// XCD-partitioned histogram: block b only counts dst in partition (b&7).
// ---------------------------------------------------------------------------
__global__ __launch_bounds__(256) void hist_kernel(
    const int* __restrict__ dst, int* __restrict__ cnt)
{
  const int part = blockIdx.x & (NPART - 1);
  const int blk  = blockIdx.x >> 3;
  const unsigned lo = part * PART_SZ;
  const int e0 = blk * CHUNK;
  const int e1 = min(e0 + CHUNK, NE);
  for (int e = e0 + threadIdx.x; e < e1; e += 256) {
    const int d = dst[e];
    if ((unsigned)(d - lo) < (unsigned)PART_SZ) atomicAdd(&cnt[d], 1);
  }
}

__global__ __launch_bounds__(1024) void scan_block_sums(
    const int* __restrict__ cnt, int* __restrict__ bsum)
{
  __shared__ int lds[1024];
  const int i = blockIdx.x * 1024 + threadIdx.x;
  lds[threadIdx.x] = (i < NN) ? cnt[i] : 0;
  __syncthreads();
  for (int o = 512; o > 0; o >>= 1) {
    if (threadIdx.x < o) lds[threadIdx.x] += lds[threadIdx.x + o];
    __syncthreads();
  }
  if (threadIdx.x == 0) bsum[blockIdx.x] = lds[0];
}

__global__ void scan_partials(int* __restrict__ bsum, int nb)
{
  __shared__ int lds[128];
  const int t = threadIdx.x;
  const int v = (t < nb) ? bsum[t] : 0;
  lds[t] = v;
  __syncthreads();
  int x = v;
  for (int o = 1; o < 128; o <<= 1) {
    const int y = (t >= o) ? lds[t - o] : 0;
    __syncthreads();
    x += y;
    lds[t] = x;
    __syncthreads();
  }
  if (t < nb) bsum[t] = x - v;  // exclusive
}

__global__ __launch_bounds__(1024) void scan_final(
    const int* __restrict__ cnt, const int* __restrict__ bsum,
    int* __restrict__ rs, int* __restrict__ next)
{
  __shared__ int lds[1024];
  const int t = threadIdx.x;
  const int i = blockIdx.x * 1024 + t;
  const int v = (i < NN) ? cnt[i] : 0;
  lds[t] = v;
  __syncthreads();
  int x = v;
  for (int o = 1; o < 1024; o <<= 1) {
    const int y = (t >= o) ? lds[t - o] : 0;
    __syncthreads();
    x += y;
    lds[t] = x;
    __syncthreads();
  }
  const int excl = x - v + bsum[blockIdx.x];
  if (i < NN) { rs[i] = excl; next[i] = excl; }
  if (i == NN - 1) rs[NN] = excl + v;
}

// ---------------------------------------------------------------------------
// XCD-partitioned scatter (unchanged from R3).
// ---------------------------------------------------------------------------
__global__ __launch_bounds__(256) void scatter_kernel(
    const int* __restrict__ src, const int* __restrict__ dst,
    int* __restrict__ next, int* __restrict__ csr_src)
{
  const int part = blockIdx.x & (NPART - 1);
  const int blk  = blockIdx.x >> 3;
  const unsigned lo = part * PART_SZ;
  const int e0 = blk * CHUNK;
  const int e1 = min(e0 + CHUNK, NE);
  for (int e = e0 + threadIdx.x; e < e1; e += 256) {
    const int d = dst[e];
    if ((unsigned)(d - lo) < (unsigned)PART_SZ) {
      const int pos = atomicAdd(&next[d], 1);
      csr_src[pos] = src[e];
    }
  }
}

// ---------------------------------------------------------------------------
// Aggregation: one wave per destination node. 3-stage, 4-edge-wide pipeline:
//   stage1: uniform idx loads for batch b+2
//   stage2: attn (uniform) + row (vector) loads for batch b+1
//   stage3: compute batch b
// No dependent-load chain inside an iteration; tails masked branch-free.
// ---------------------------------------------------------------------------
__global__ __launch_bounds__(256) void aggregate_kernel(
    const int* __restrict__ rs, const int* __restrict__ csr_src,
    const float2* __restrict__ attn_s, const float2* __restrict__ attn_d,
    const ushort* __restrict__ src_fc, float* __restrict__ out)
{
  int wid = (int)((blockIdx.x * (size_t)blockDim.x + threadIdx.x) >> 6);
  if (wid >= NN) return;
  wid = __builtin_amdgcn_readfirstlane(wid);
  const int lane = threadIdx.x & 63;
  const int start = rs[wid];
  const int end = rs[wid + 1];
  const int deg = end - start;
  if (deg == 0) return;   // isolated node: out already = feat_dst_fc

  const float2 ad = attn_d[wid];
  const bool h0 = (lane < 32);
  const float adh = h0 ? ad.x : ad.y;
  const int nb = (deg + 3) >> 2;

  struct Idx { int s0, s1, s2, s3; };
  struct Dat { float2 a0, a1, a2, a3; uint32_t r0, r1, r2, r3; };

  auto loadIdx = [&](int b) {
    const int base = start + b * 4;
    Idx I;
    I.s0 = csr_src[base];
    I.s1 = csr_src[(base + 1 < end) ? base + 1 : start];
    I.s2 = csr_src[(base + 2 < end) ? base + 2 : start];
    I.s3 = csr_src[(base + 3 < end) ? base + 3 : start];
    return I;
  };
  auto loadDat = [&](const Idx& I) {
    Dat D;
    D.a0 = attn_s[I.s0]; D.a1 = attn_s[I.s1];
    D.a2 = attn_s[I.s2]; D.a3 = attn_s[I.s3];
    D.r0 = *(const uint32_t*)(src_fc + (size_t)I.s0 * 128 + 2 * lane);
    D.r1 = *(const uint32_t*)(src_fc + (size_t)I.s1 * 128 + 2 * lane);
    D.r2 = *(const uint32_t*)(src_fc + (size_t)I.s2 * 128 + 2 * lane);
    D.r3 = *(const uint32_t*)(src_fc + (size_t)I.s3 * 128 + 2 * lane);
    return D;
  };

  float acc0 = 0.0f, acc1 = 0.0f, denom = 0.0f;
  auto edge = [&](float2 as_c, uint32_t rb_c, bool valid) {
    float e = (h0 ? as_c.x : as_c.y) + adh;
    e = (e > 0.0f) ? e : NEG * e;
    float wgt = __expf(e);
    wgt = valid ? wgt : 0.0f;
    denom += wgt;
    acc0 = fmaf(__uint_as_float(rb_c << 16), wgt, acc0);          // feat 2*lane
    acc1 = fmaf(__uint_as_float(rb_c & 0xffff0000u), wgt, acc1);  // feat 2*lane+1
  };

  Idx iNext = loadIdx(0);
  Dat dCur  = loadDat(iNext);
  iNext = (nb > 1) ? loadIdx(1) : iNext;

  for (int b = 0; b < nb; ++b) {
    Dat dNext = dCur;
    if (b + 1 < nb) dNext = loadDat(iNext);
    Idx iN2 = iNext;
    if (b + 2 < nb) iN2 = loadIdx(b + 2);
    const int base = start + b * 4;
    edge(dCur.a0, dCur.r0, true);
    edge(dCur.a1, dCur.r1, base + 1 < end);
    edge(dCur.a2, dCur.r2, base + 2 < end);
    edge(dCur.a3, dCur.r3, base + 3 < end);
    dCur = dNext;
    iNext = iN2;
  }

  const float inv = 1.0f / denom;
  float2* po = (float2*)(out + (size_t)wid * 128 + 2 * lane);
  float2 cur = *po;
  cur.x = fmaf(acc0, inv, cur.x);
  cur.y = fmaf(acc1, inv, cur.y);
  *po = cur;
}

// ---------------------------------------------------------------------------
extern "C" void kernel_launch(void* const* d_in, const int* in_sizes, int n_in,
                              void* d_out, int out_size, void* d_ws, size_t ws_size,
                              hipStream_t stream)
{
  const float* feat    = (const float*)d_in[0];
  const int*   src_idx = (const int*)d_in[1];
  const int*   dst_idx = (const int*)d_in[2];
  const float* Wsrc    = (const float*)d_in[3];
  const float* Wdst    = (const float*)d_in[4];
  const float* bdst    = (const float*)d_in[5];
  const float* asrc    = (const float*)d_in[6];
  const float* adst    = (const float*)d_in[7];
  float* out = (float*)d_out;

  char* ws = (char*)d_ws;
  size_t off = 0;
  auto alloc = [&](size_t bytes) -> void* {
    void* p = ws + off;
    off = (off + bytes + 255) & ~(size_t)255;
    return p;
  };
  ushort* src_fc  = (ushort*)alloc((size_t)NN * 128 * sizeof(ushort)); // 25.6 MB
  float*  attn_s  = (float*)alloc((size_t)NN * 2 * sizeof(float));
  float*  attn_d  = (float*)alloc((size_t)NN * 2 * sizeof(float));
  int*    cnt     = (int*)alloc((size_t)NN * sizeof(int));
  int*    rs      = (int*)alloc((size_t)(NN + 1) * sizeof(int));
  int*    next    = (int*)alloc((size_t)NN * sizeof(int));
  int*    csr_src = (int*)alloc((size_t)NE * sizeof(int));             // 6.4 MB
  int*    bsum    = (int*)alloc(128 * sizeof(int));
  ushort* wb      = (ushort*)alloc((size_t)256 * 128 * sizeof(ushort));

  hipMemsetAsync(cnt, 0, (size_t)NN * sizeof(int), stream);

  cvt_w_kernel<<<16, 256, 0, stream>>>(Wsrc, Wdst, wb);
  gemm_kernel<<<2048, 256, 0, stream>>>(feat, wb, bdst, src_fc, out);
  attn_kernel<<<(NN * 4 + 255) / 256, 256, 0, stream>>>(feat, asrc, adst, attn_s, attn_d);
  hist_kernel<<<BLK_PER_PART * NPART, 256, 0, stream>>>(dst_idx, cnt);

  constexpr int NB = (NN + 1023) / 1024;  // 98
  scan_block_sums<<<NB, 1024, 0, stream>>>(cnt, bsum);
  scan_partials<<<1, 128, 0, stream>>>(bsum, NB);
  scan_final<<<NB, 1024, 0, stream>>>(cnt, bsum, rs, next);

  scatter_kernel<<<BLK_PER_PART * NPART, 256, 0, stream>>>(src_idx, dst_idx, next, csr_src);
  aggregate_kernel<<<(NN * 64) / 256, 256, 0, stream>>>(
      rs, csr_src, (const float2*)attn_s, (const float2*)attn_d, src_fc, out);
}

// Round 6
// 314.939 us; speedup vs baseline: 2.0796x; 1.0182x over previous
//
#include <hip/hip_runtime.h>
#include <cstdint>
#include <cstddef>

static constexpr int NN = 100000;
static constexpr int NE = 1600000;
static constexpr float NEG = 0.2f;
static constexpr int NPART = 8;                 // == #XCDs
static constexpr int PART_SZ = NN / NPART;      // 12500
static constexpr int BLK_PER_PART = 256;
static constexpr int CHUNK = NE / BLK_PER_PART; // 6250

typedef __attribute__((ext_vector_type(8))) short short8v;   // 8 bf16 (4 VGPRs)
typedef __attribute__((ext_vector_type(4))) float floatx4;   // 4 f32 acc

// ---------------------------------------------------------------------------
__device__ inline short8v cvt8(const float4 a, const float4 b)
{
  const float v[8] = {a.x, a.y, a.z, a.w, b.x, b.y, b.z, b.w};
  uint32_t q[8];
#pragma unroll
  for (int j = 0; j < 8; ++j) {
    uint32_t u = __float_as_uint(v[j]);
    u += 0x7fff + ((u >> 16) & 1);   // round-to-nearest-even
    q[j] = u >> 16;
  }
  union { uint32_t u[4]; short8v s; } r;
  r.u[0] = q[0] | (q[1] << 16);
  r.u[1] = q[2] | (q[3] << 16);
  r.u[2] = q[4] | (q[5] << 16);
  r.u[3] = q[6] | (q[7] << 16);
  return r.s;
}

__device__ inline ushort cvt1(float x)
{
  uint32_t u = __float_as_uint(x);
  u += 0x7fff + ((u >> 16) & 1);
  return (ushort)(u >> 16);
}

// ---------------------------------------------------------------------------
__global__ __launch_bounds__(256) void cvt_w_kernel(
    const float* __restrict__ Wsrc, const float* __restrict__ Wdst,
    ushort* __restrict__ wb)
{
  const int i = (blockIdx.x * 256 + threadIdx.x) * 8;
  if (i >= 32768) return;
  const float* src = (i < 16384) ? (Wsrc + i) : (Wdst + (i - 16384));
  float4 a = *(const float4*)(src);
  float4 b = *(const float4*)(src + 4);
  short8v s = cvt8(a, b);
  *(short8v*)(wb + i) = s;
}

// ---------------------------------------------------------------------------
// MFMA projection GEMM: A = feat (f32 -> bf16 in-flight), B = wb register-
// resident. Cols 0-127 -> src_fc (bf16), cols 128-255 -> out (f32, + bias).
// ---------------------------------------------------------------------------
__global__ __launch_bounds__(256) void gemm_kernel(
    const float* __restrict__ feat, const ushort* __restrict__ wb,
    const float* __restrict__ bdst,
    ushort* __restrict__ src_fc, float* __restrict__ out)
{
  const int lane = threadIdx.x & 63;
  const int w    = threadIdx.x >> 6;       // wave 0..3
  const int c0   = w * 64;
  const int colq = lane & 15;
  const int kgrp = lane >> 4;

  short8v bf[4][4];
#pragma unroll
  for (int nt = 0; nt < 4; ++nt)
#pragma unroll
    for (int kt = 0; kt < 4; ++kt)
      bf[nt][kt] = *(const short8v*)(wb + (size_t)(c0 + nt * 16 + colq) * 128
                                        + kt * 32 + kgrp * 8);

  float bias[4];
#pragma unroll
  for (int nt = 0; nt < 4; ++nt) {
    const int col = c0 + nt * 16 + colq;
    bias[nt] = (col >= 128) ? bdst[col - 128] : 0.0f;
  }
  const bool is_dst = (c0 >= 128);

  for (int mt = blockIdx.x; mt < NN / 16; mt += gridDim.x) {
    const int row0 = mt * 16;
    short8v af[4];
#pragma unroll
    for (int kt = 0; kt < 4; ++kt) {
      const float* ap = feat + (size_t)(row0 + colq) * 128 + kt * 32 + kgrp * 8;
      float4 a = *(const float4*)ap;
      float4 b = *(const float4*)(ap + 4);
      af[kt] = cvt8(a, b);
    }
    floatx4 acc[4] = {{0,0,0,0},{0,0,0,0},{0,0,0,0},{0,0,0,0}};
#pragma unroll
    for (int kt = 0; kt < 4; ++kt)
#pragma unroll
      for (int nt = 0; nt < 4; ++nt)
        acc[nt] = __builtin_amdgcn_mfma_f32_16x16x32_bf16(af[kt], bf[nt][kt],
                                                          acc[nt], 0, 0, 0);
    // C/D: col = lane&15, row = (lane>>4)*4 + reg
#pragma unroll
    for (int nt = 0; nt < 4; ++nt) {
      const int col = c0 + nt * 16 + colq;
#pragma unroll
      for (int j = 0; j < 4; ++j) {
        const int rr = row0 + kgrp * 4 + j;
        if (!is_dst) src_fc[(size_t)rr * 128 + col] = cvt1(acc[nt][j]);
        else         out[(size_t)rr * 128 + (col - 128)] = acc[nt][j] + bias[nt];
      }
    }
  }
}

// ---------------------------------------------------------------------------
// Attention projections, wave-per-node: reads each feat row exactly once.
// Lane l holds feat[k=2l,2l+1] and the matching a-vector elements (preloaded,
// loop-invariant); 4 partial dots -> 6-step shuffle reduce -> lane 0 stores.
// ---------------------------------------------------------------------------
__global__ __launch_bounds__(256) void attn_kernel(
    const float* __restrict__ feat, const float* __restrict__ asrc,
    const float* __restrict__ adst, float2* __restrict__ attn_s,
    float2* __restrict__ attn_d)
{
  const int lane = threadIdx.x & 63;
  const int k0 = 2 * lane;
  const float a0x = asrc[k0],       a0y = asrc[k0 + 1];
  const float a1x = asrc[128 + k0], a1y = asrc[128 + k0 + 1];
  const float d0x = adst[k0],       d0y = adst[k0 + 1];
  const float d1x = adst[128 + k0], d1y = adst[128 + k0 + 1];

  const int gw = (int)((blockIdx.x * 256 + threadIdx.x) >> 6);
  const int nw = (int)((gridDim.x * 256) >> 6);
  for (int n = gw; n < NN; n += nw) {
    const float2 f = *(const float2*)(feat + (size_t)n * 128 + k0);
    float p0 = f.x * a0x + f.y * a0y;
    float p1 = f.x * a1x + f.y * a1y;
    float p2 = f.x * d0x + f.y * d0y;
    float p3 = f.x * d1x + f.y * d1y;
#pragma unroll
    for (int o = 32; o > 0; o >>= 1) {
      p0 += __shfl_xor(p0, o, 64);
      p1 += __shfl_xor(p1, o, 64);
      p2 += __shfl_xor(p2, o, 64);
      p3 += __shfl_xor(p3, o, 64);
    }
    if (lane == 0) {
      attn_s[n] = make_float2(p0, p1);
      attn_d[n] = make_float2(p2, p3);
    }
  }
}

// ---------------------------------------------------------------------------
// XCD-partitioned histogram: block b only counts dst in partition (b&7).
// ---------------------------------------------------------------------------
__global__ __launch_bounds__(256) void hist_kernel(
    const int* __restrict__ dst, int* __restrict__ cnt)
{
  const int part = blockIdx.x & (NPART - 1);
  const int blk  = blockIdx.x >> 3;
  const unsigned lo = part * PART_SZ;
  const int e0 = blk * CHUNK;
  const int e1 = min(e0 + CHUNK, NE);
  for (int e = e0 + threadIdx.x; e < e1; e += 256) {
    const int d = dst[e];
    if ((unsigned)(d - lo) < (unsigned)PART_SZ) atomicAdd(&cnt[d], 1);
  }
}

__global__ __launch_bounds__(1024) void scan_block_sums(
    const int* __restrict__ cnt, int* __restrict__ bsum)
{
  __shared__ int lds[1024];
  const int i = blockIdx.x * 1024 + threadIdx.x;
  lds[threadIdx.x] = (i < NN) ? cnt[i] : 0;
  __syncthreads();
  for (int o = 512; o > 0; o >>= 1) {
    if (threadIdx.x < o) lds[threadIdx.x] += lds[threadIdx.x + o];
    __syncthreads();
  }
  if (threadIdx.x == 0) bsum[blockIdx.x] = lds[0];
}

__global__ void scan_partials(int* __restrict__ bsum, int nb)
{
  __shared__ int lds[128];
  const int t = threadIdx.x;
  const int v = (t < nb) ? bsum[t] : 0;
  lds[t] = v;
  __syncthreads();
  int x = v;
  for (int o = 1; o < 128; o <<= 1) {
    const int y = (t >= o) ? lds[t - o] : 0;
    __syncthreads();
    x += y;
    lds[t] = x;
    __syncthreads();
  }
  if (t < nb) bsum[t] = x - v;  // exclusive
}

__global__ __launch_bounds__(1024) void scan_final(
    const int* __restrict__ cnt, const int* __restrict__ bsum,
    int* __restrict__ rs, int* __restrict__ next)
{
  __shared__ int lds[1024];
  const int t = threadIdx.x;
  const int i = blockIdx.x * 1024 + t;
  const int v = (i < NN) ? cnt[i] : 0;
  lds[t] = v;
  __syncthreads();
  int x = v;
  for (int o = 1; o < 1024; o <<= 1) {
    const int y = (t >= o) ? lds[t - o] : 0;
    __syncthreads();
    x += y;
    lds[t] = x;
    __syncthreads();
  }
  const int excl = x - v + bsum[blockIdx.x];
  if (i < NN) { rs[i] = excl; next[i] = excl; }
  if (i == NN - 1) rs[NN] = excl + v;
}

// ---------------------------------------------------------------------------
// XCD-partitioned scatter + edge-weight precompute. Per edge stores a 16 B
// record {src_byte_offset, w0, w1, 0} where w = exp(leaky(as+ad)). attn
// tables are L2-resident; records land in partition-local L2 lines.
// ---------------------------------------------------------------------------
__global__ __launch_bounds__(256) void scatter_kernel(
    const int* __restrict__ src, const int* __restrict__ dst,
    const float2* __restrict__ attn_s, const float2* __restrict__ attn_d,
    int* __restrict__ next, uint4* __restrict__ edges)
{
  const int part = blockIdx.x & (NPART - 1);
  const int blk  = blockIdx.x >> 3;
  const unsigned lo = part * PART_SZ;
  const int e0 = blk * CHUNK;
  const int e1 = min(e0 + CHUNK, NE);
  for (int e = e0 + threadIdx.x; e < e1; e += 256) {
    const int d = dst[e];
    if ((unsigned)(d - lo) < (unsigned)PART_SZ) {
      const int s = src[e];
      const float2 as = attn_s[s];
      const float2 ad = attn_d[d];
      float l0 = as.x + ad.x;
      float l1 = as.y + ad.y;
      l0 = (l0 > 0.0f) ? l0 : NEG * l0;
      l1 = (l1 > 0.0f) ? l1 : NEG * l1;
      const float w0 = __expf(l0);
      const float w1 = __expf(l1);
      const int pos = atomicAdd(&next[d], 1);
      edges[pos] = make_uint4((unsigned)(s * 256),
                              __float_as_uint(w0), __float_as_uint(w1), 0u);
    }
  }
}

// ---------------------------------------------------------------------------
// Aggregation: one wave per destination node. Edge weights are precomputed;
// inner loop = uniform 16 B record load + one row gather + 2 FMA + 1 add.
// 3-stage, 8-edge-wide pipeline; tails masked via scalar weight zeroing.
// ---------------------------------------------------------------------------
__global__ __launch_bounds__(256) void aggregate_kernel(
    const int* __restrict__ rs, const uint4* __restrict__ edges,
    const ushort* __restrict__ src_fc, float* __restrict__ out)
{
  int wid = (int)((blockIdx.x * (size_t)blockDim.x + threadIdx.x) >> 6);
  if (wid >= NN) return;
  wid = __builtin_amdgcn_readfirstlane(wid);
  const int lane = threadIdx.x & 63;
  const int start = rs[wid];
  const int end = rs[wid + 1];
  const int deg = end - start;
  if (deg == 0) return;   // isolated node: out already = feat_dst_fc

  const bool h0 = (lane < 32);
  const unsigned lane4 = lane * 4;          // byte offset within bf16 row
  const char* fcb = (const char*)src_fc;
  const int nb = (deg + 7) >> 3;

  struct Batch { uint4 e[8]; };
  struct Rows  { uint32_t r[8]; };

  auto loadE = [&](int b, Batch& B) {
    const int base = start + b * 8;
#pragma unroll
    for (int j = 0; j < 8; ++j) {
      const int idx = (base + j < end) ? base + j : start;
      B.e[j] = edges[idx];                   // uniform -> s_load_dwordx4
    }
  };
  auto loadR = [&](const Batch& B, Rows& R) {
#pragma unroll
    for (int j = 0; j < 8; ++j)
      R.r[j] = *(const uint32_t*)(fcb + (B.e[j].x + lane4));
  };

  float acc0 = 0.0f, acc1 = 0.0f, dh = 0.0f;
  auto compute = [&](int b, const Batch& B, const Rows& R) {
    const int rem = deg - b * 8;
#pragma unroll
    for (int j = 0; j < 8; ++j) {
      const bool valid = j < rem;            // scalar
      const float w0 = valid ? __uint_as_float(B.e[j].y) : 0.0f;
      const float w1 = valid ? __uint_as_float(B.e[j].z) : 0.0f;
      const float wh = h0 ? w0 : w1;
      dh += wh;
      acc0 = fmaf(__uint_as_float(R.r[j] << 16), wh, acc0);
      acc1 = fmaf(__uint_as_float(R.r[j] & 0xffff0000u), wh, acc1);
    }
  };

  Batch bA, bB;
  Rows rA;
  loadE(0, bA);
  loadR(bA, rA);
  if (nb > 1) loadE(1, bB); else bB = bA;

  for (int b = 0; b < nb; ++b) {
    Rows rB = rA;
    if (b + 1 < nb) loadR(bB, rB);
    Batch bC = bB;
    if (b + 2 < nb) loadE(b + 2, bC);
    compute(b, bA, rA);
    bA = bB; rA = rB; bB = bC;
  }

  const float inv = 1.0f / dh;
  float2* po = (float2*)(out + (size_t)wid * 128 + 2 * lane);
  float2 cur = *po;
  cur.x = fmaf(acc0, inv, cur.x);
  cur.y = fmaf(acc1, inv, cur.y);
  *po = cur;
}

// ---------------------------------------------------------------------------
extern "C" void kernel_launch(void* const* d_in, const int* in_sizes, int n_in,
                              void* d_out, int out_size, void* d_ws, size_t ws_size,
                              hipStream_t stream)
{
  const float* feat    = (const float*)d_in[0];
  const int*   src_idx = (const int*)d_in[1];
  const int*   dst_idx = (const int*)d_in[2];
  const float* Wsrc    = (const float*)d_in[3];
  const float* Wdst    = (const float*)d_in[4];
  const float* bdst    = (const float*)d_in[5];
  const float* asrc    = (const float*)d_in[6];
  const float* adst    = (const float*)d_in[7];
  float* out = (float*)d_out;

  char* ws = (char*)d_ws;
  size_t off = 0;
  auto alloc = [&](size_t bytes) -> void* {
    void* p = ws + off;
    off = (off + bytes + 255) & ~(size_t)255;
    return p;
  };
  ushort* src_fc  = (ushort*)alloc((size_t)NN * 128 * sizeof(ushort)); // 25.6 MB
  float*  attn_s  = (float*)alloc((size_t)NN * 2 * sizeof(float));
  float*  attn_d  = (float*)alloc((size_t)NN * 2 * sizeof(float));
  int*    cnt     = (int*)alloc((size_t)NN * sizeof(int));
  int*    rs      = (int*)alloc((size_t)(NN + 1) * sizeof(int));
  int*    next    = (int*)alloc((size_t)NN * sizeof(int));
  uint4*  edges   = (uint4*)alloc((size_t)NE * sizeof(uint4));         // 25.6 MB
  int*    bsum    = (int*)alloc(128 * sizeof(int));
  ushort* wb      = (ushort*)alloc((size_t)256 * 128 * sizeof(ushort));

  hipMemsetAsync(cnt, 0, (size_t)NN * sizeof(int), stream);

  cvt_w_kernel<<<16, 256, 0, stream>>>(Wsrc, Wdst, wb);
  gemm_kernel<<<2048, 256, 0, stream>>>(feat, wb, bdst, src_fc, out);
  attn_kernel<<<1024, 256, 0, stream>>>(feat, asrc, adst,
                                        (float2*)attn_s, (float2*)attn_d);
  hist_kernel<<<BLK_PER_PART * NPART, 256, 0, stream>>>(dst_idx, cnt);

  constexpr int NB = (NN + 1023) / 1024;  // 98
  scan_block_sums<<<NB, 1024, 0, stream>>>(cnt, bsum);
  scan_partials<<<1, 128, 0, stream>>>(bsum, NB);
  scan_final<<<NB, 1024, 0, stream>>>(cnt, bsum, rs, next);

  scatter_kernel<<<BLK_PER_PART * NPART, 256, 0, stream>>>(
      src_idx, dst_idx, (const float2*)attn_s, (const float2*)attn_d,
      next, edges);
  aggregate_kernel<<<(NN * 64) / 256, 256, 0, stream>>>(rs, edges, src_fc, out);
}